// Round 4
// baseline (198.090 us; speedup 1.0000x reference)
//
#include <hip/hip_runtime.h>

typedef __fp16 fp16x2 __attribute__((ext_vector_type(2)));   // cvt_pkrtz result type
typedef _Float16 half8 __attribute__((ext_vector_type(8)));
typedef float floatx4 __attribute__((ext_vector_type(4)));

namespace {

constexpr int NODES = 512;   // nodes per graph
constexpr int DIM   = 256;   // latent dim (floats)
constexpr int BM    = 128;   // block tile (rows and cols)
constexpr int BKF   = 32;    // K-step in floats: fp32 row = 128 B = 8 x 16-B chunks
constexpr int PANEL = BM * BKF;   // 4096 floats = 16 KB

union Cvt8 { fp16x2 h2[4]; half8 h8; };

__device__ inline half8 pack8(const floatx4 f0, const floatx4 f1) {
  Cvt8 c;
  c.h2[0] = __builtin_amdgcn_cvt_pkrtz(f0.x, f0.y);
  c.h2[1] = __builtin_amdgcn_cvt_pkrtz(f0.z, f0.w);
  c.h2[2] = __builtin_amdgcn_cvt_pkrtz(f1.x, f1.y);
  c.h2[3] = __builtin_amdgcn_cvt_pkrtz(f1.z, f1.w);
  return c.h8;
}

// async 16-B global -> LDS DMA; LDS dest = wave-uniform base + lane*16
__device__ inline void async_ld16(const void* g, void* lds) {
  __builtin_amdgcn_global_load_lds(
      (const __attribute__((address_space(1))) unsigned int*)g,
      (__attribute__((address_space(3))) unsigned int*)lds,
      16, 0, 0);
}

__device__ inline float sigmoidf(float x) {
  return __builtin_amdgcn_rcpf(1.0f + __expf(-x));
}

// ---------- fused kernel: fp32 stage -> fp16 fragments -> MFMA -> sigmoid ----
// ONE kernel, no fp16 intermediate in HBM. C = Z Z^T exactly symmetric ->
// only tiles tn<=tm: grid = 128 graphs x 10 tiles = 1280 blocks, 4 waves each,
// wave = 64x64 sub-tile via 4x4 mfma_f32_16x16x32_f16.
//
// Round-4 change: DOUBLE-BUFFERED 2-phase K-loop (T3-minimum). Per K-step:
//   STAGE(next K-step -> other buffer)   <- async loads issued FIRST
//   compute(current buffer)              <- ds_read + cvt + MFMA hide the load
//   __syncthreads()                      <- single barrier: drains vmcnt AFTER
//                                           ~400 cy of compute, not before it
// BKF=32 so 4 buffers (A0,A1,B0,B1) = 64 KB LDS -> still 2 blocks/CU.
//
// Staging: global_load_lds (16 B), LDS linear [row][chunk0..7]; source chunk
// pre-swizzled cs = c ^ (row&7); fragment reads XOR the same way -> per-16-lane
// phase each bank is 2-way (free, m136).
// Diagonal tiles stage ONE panel (A==B). Off-diagonal tiles write both output
// blocks: (tm,tn) via float4 rows, (tn,tm) scalar mirror. Normal stores.
__global__ __launch_bounds__(256, 2)
void fused_kernel(const float* __restrict__ z, float* __restrict__ out) {
  __shared__ __align__(16) float As[2 * PANEL];   // 32 KB
  __shared__ __align__(16) float Bs[2 * PANEL];   // 32 KB

  const int bid  = blockIdx.x;
  const int x    = bid & 7;            // XCD
  const int j    = bid >> 3;           // 0..159
  const int ggrp = j / 10;             // 0..15
  const int t    = j - ggrp * 10;      // 0..9, unique tile id
  const int g    = x + 8 * ggrp;       // graph, g%8 == XCD

  int tn, tm;
  if (t < 4)      { tn = 0; tm = t; }
  else if (t < 7) { tn = 1; tm = t - 3; }
  else if (t < 9) { tn = 2; tm = t - 5; }
  else            { tn = 3; tm = 3; }
  const bool diag = (tn == tm);

  const int tid  = threadIdx.x;
  const int lane = tid & 63;
  const int wave = tid >> 6;
  const int wRow = wave >> 1;
  const int wCol = wave & 1;
  const int lrow = lane & 15;
  const int quad = lane >> 4;

  const float* zA = z + ((size_t)g * NODES + tn * BM) * DIM;
  const float* zB = z + ((size_t)g * NODES + tm * BM) * DIM;

  // staging: 16 insts/panel/K-step (1 KB each = 8 rows), 4 insts per wave.
  // lane -> local row = lane>>3 (0..7), LDS chunk = lane&7,
  // source chunk pre-swizzled: cs = (lane&7) ^ (lane>>3)  (row&7 == lane>>3).
  const int    sRow = lane >> 3;
  const int    sCs  = (lane & 7) ^ sRow;
  const size_t sOff = (size_t)sRow * DIM + sCs * 4;   // floats

  // fragment-read constants: row_i = wRow*64 + i*16 + lrow (row&7 == lrow&7),
  // physical chunks for logical k-slice quad*8..quad*8+7:
  const int c0 = (quad * 2)     ^ (lrow & 7);
  const int c1 = (quad * 2 + 1) ^ (lrow & 7);
  const int rA = (wRow * 64 + lrow) * BKF;
  const int rB = (wCol * 64 + lrow) * BKF;

  floatx4 acc[4][4];
#pragma unroll
  for (int i = 0; i < 4; ++i)
#pragma unroll
    for (int jj = 0; jj < 4; ++jj)
      acc[i][jj] = (floatx4){0.f, 0.f, 0.f, 0.f};

  auto stage = [&](int kk, float* dA, float* dB) {
#pragma unroll
    for (int it = 0; it < 4; ++it) {
      const int q = wave * 4 + it;                   // 0..15, rows q*8..q*8+7
      async_ld16(zA + (size_t)q * 8 * DIM + kk + sOff, dA + q * 256);
      if (!diag)
        async_ld16(zB + (size_t)q * 8 * DIM + kk + sOff, dB + q * 256);
    }
  };

  auto compute = [&](const float* pA, const float* pB) {
    const float* pBs = diag ? pA : pB;
    half8 af[4], bf[4];
#pragma unroll
    for (int i = 0; i < 4; ++i) {
      const int base = rA + i * 16 * BKF;
      const floatx4 a0 = *reinterpret_cast<const floatx4*>(&pA[base + c0 * 4]);
      const floatx4 a1 = *reinterpret_cast<const floatx4*>(&pA[base + c1 * 4]);
      af[i] = pack8(a0, a1);
    }
#pragma unroll
    for (int jj = 0; jj < 4; ++jj) {
      const int base = rB + jj * 16 * BKF;
      const floatx4 b0 = *reinterpret_cast<const floatx4*>(&pBs[base + c0 * 4]);
      const floatx4 b1 = *reinterpret_cast<const floatx4*>(&pBs[base + c1 * 4]);
      bf[jj] = pack8(b0, b1);
    }
#pragma unroll
    for (int i = 0; i < 4; ++i)
#pragma unroll
      for (int jj = 0; jj < 4; ++jj)
        acc[i][jj] = __builtin_amdgcn_mfma_f32_16x16x32_f16(af[i], bf[jj], acc[i][jj], 0, 0, 0);
  };

  float* A0 = As;  float* A1 = As + PANEL;
  float* B0 = Bs;  float* B1 = Bs + PANEL;

  // prologue: stage K-step 0
  stage(0, A0, B0);
  __syncthreads();

  // 8 K-steps, unrolled in pairs so buffer selection is compile-time
#pragma unroll
  for (int tt = 0; tt < 4; ++tt) {
    stage((2 * tt + 1) * BKF, A1, B1);     // issue next-step loads FIRST
    compute(A0, B0);                       // ds_read+cvt+MFMA hide them
    __syncthreads();                       // drains vmcnt: buf1 ready
    if (tt < 3) stage((2 * tt + 2) * BKF, A0, B0);
    compute(A1, B1);
    __syncthreads();
  }

  // epilogue: sigmoid once; write block (tm,tn) transposed with float4 rows;
  // off-diagonal also writes the mirror block (tn,tm) with scalar stores.
  // acc[i][j][r] = C[n, m], n = tn*128 + wRow*64 + i*16 + quad*4 + r
  //                         m = tm*128 + wCol*64 + j*16 + lrow
  float* outg = out + (size_t)g * NODES * NODES;
  const int nBase = tn * BM + wRow * 64;
  const int mBase = tm * BM + wCol * 64;
#pragma unroll
  for (int jj = 0; jj < 4; ++jj) {
    const int m = mBase + jj * 16 + lrow;
    float* rowp = outg + (size_t)m * NODES;
#pragma unroll
    for (int i = 0; i < 4; ++i) {
      const int n0 = nBase + i * 16 + quad * 4;
      floatx4 v;
#pragma unroll
      for (int r = 0; r < 4; ++r)
        v[r] = sigmoidf(acc[i][jj][r]);
      *reinterpret_cast<floatx4*>(rowp + n0) = v;          // out[m][n0..n0+3]
      if (!diag) {
#pragma unroll
        for (int r = 0; r < 4; ++r)
          outg[(size_t)(n0 + r) * NODES + m] = v[r];       // out[n][m]
      }
    }
  }
}

} // namespace

extern "C" void kernel_launch(void* const* d_in, const int* in_sizes, int n_in,
                              void* d_out, int out_size, void* d_ws, size_t ws_size,
                              hipStream_t stream) {
  const float* z = (const float*)d_in[0];
  float* out = (float*)d_out;
  (void)d_ws; (void)ws_size;
  hipLaunchKernelGGL(fused_kernel, dim3(128 * 10), dim3(256), 0, stream, z, out);
}